// Round 6
// baseline (155.137 us; speedup 1.0000x reference)
//
#include <hip/hip_runtime.h>

// Mutual information, N=8 images 384x384, 50 soft bins.
// Single fused kernel (+ 32KB memset): 28 even sigmoid edges per element
// (t_j = sigmoid(10v-0.2j) x256), G = te_x . te_y^T via 16x16x32 MFMA
// (32x32-padded), atomic reduction into hg[8][32][32]; hgram = W G W^T with
// W = D*M (cubic-interp odd edges, 4-banded, coeffs {1,7,-9,1}/16 even,
// {-1,9,-7,-1}/16 odd) applied in a last-block finalize (done-counter).
// Marginals telescope: sum_b W[b] = e_1 - e_26.
//
// R6 vs R5: grid 1536->1024 (4 blocks/CU uniform), double-buffered LDS
// (1 barrier/iter, prefetched next v), finalize folded into last block
// (saves a dispatch + gap, overlaps with tail). Fill of 256MB ws by the
// harness (~42us @ 80% HBM) is a fixed floor outside our control.

#define D_TOTAL   147456
#define NBATCH    8
#define BINS      50
#define NEDGE     28                       // even edges j=-2..52
#define KSLICES   128
#define KC        128
#define SLICE_LEN (D_TOTAL / KSLICES)      // 1152
#define ITERS     (SLICE_LEN / KC)         // 9
#define LDS_STR   152                      // 76 dwords = 12 mod 32: conflict-free b128 frags
#define NBLOCKS   (KSLICES * NBATCH)       // 1024

typedef _Float16 half8 __attribute__((ext_vector_type(8)));
typedef float    f32x4 __attribute__((ext_vector_type(4)));

__global__ __launch_bounds__(256, 4) void mi_kernel(const float* __restrict__ im1,
                                                    const float* __restrict__ im2,
                                                    float* __restrict__ hg,
                                                    unsigned* __restrict__ done,
                                                    float* __restrict__ out) {
    __shared__ __align__(16) _Float16 S[2][2][32][LDS_STR];   // [buf][X/Y][row][col] 38912 B
    __shared__ unsigned last_flag;
    __shared__ float red[4];
    __shared__ float sTv;

    const int tid   = threadIdx.x;
    const int slice = blockIdx.x;
    const int n     = blockIdx.y;
    const int base  = n * D_TOTAL + slice * SLICE_LEN;

    // zero pad rows 28..31 of all 4 planes (4 rows x 152 halves = 304 dwords each)
    for (int i = tid; i < 4 * 304; i += 256) {
        const int p = i >> 8 << 8 ? 0 : 0; // (dummy to keep compiler happy about div)
        const int plane = i / 304;
        const int q = i - plane * 304;
        ((unsigned*)&S[plane >> 1][plane & 1][28][0])[q] = 0u;
    }

    const int col = tid & 127;
    const int isY = tid >> 7;
    const float* src = isY ? im2 : im1;

    const int lane = tid & 63;
    const int w    = tid >> 6;
    const int r0   = (w & 1) << 4;            // G row strip (X edge)
    const int c0   = (w >> 1) << 4;           // G col strip (Y edge)
    const int frow = lane & 15;
    const int kg   = (lane >> 4) << 3;

    f32x4 acc = {0.f, 0.f, 0.f, 0.f};

    // stage: one element -> 28 even-edge sigmoids (x256, f16) into buf
    auto stage = [&](int buf, float v) {
        _Float16* dst = &S[buf][isY][0][col];
        float E = __builtin_amdgcn_exp2f(v * -14.426950408889634f);   // e^{-10v}
        float u = E * 0.6703200460356393f;                            // e^{-0.4}: edge j=-2
        #pragma unroll
        for (int i = 0; i < NEDGE; ++i) {
            float t = __builtin_amdgcn_rcpf(__builtin_fmaf(u, 0.00390625f, 0.00390625f));
            dst[i * LDS_STR] = (_Float16)t;   // 256/(1+u)
            u *= 1.4918246976412703f;         // e^{0.4} per even edge
        }
    };

    stage(0, src[base + col]);
    for (int it = 0; it < ITERS; ++it) {
        float vn = 0.f;
        if (it + 1 < ITERS) vn = src[base + (it + 1) * KC + col];   // prefetch before barrier
        __syncthreads();   // buf[it&1] fully staged; prior MFMA readers of this buf are done
        const int buf = it & 1;
        #pragma unroll
        for (int ks = 0; ks < 4; ++ks) {
            const int k0 = ks * 32 + kg;
            half8 a = *(const half8*)&S[buf][0][r0 + frow][k0];
            half8 b = *(const half8*)&S[buf][1][c0 + frow][k0];
            acc = __builtin_amdgcn_mfma_f32_16x16x32_f16(a, b, acc, 0, 0, 0);
        }
        if (it + 1 < ITERS) stage(buf ^ 1, vn);
    }

    // epilogue: atomic-add the 28x28 region of G
    {
        float* hgn = hg + n * 1024;
        const int gj = c0 + (lane & 15);
        const int ri = r0 + ((lane >> 4) << 2);
        if (gj < NEDGE) {
            #pragma unroll
            for (int r = 0; r < 4; ++r) {
                const int gi = ri + r;
                if (gi < NEDGE) atomicAdd(&hgn[gi * 32 + gj], acc[r]);
            }
        }
    }
    __threadfence();
    __syncthreads();   // vmcnt(0) drain: this block's G atomics complete
    if (tid == 0) last_flag = (atomicAdd(done, 1u) == NBLOCKS - 1) ? 1u : 0u;
    __syncthreads();
    if (!last_flag) return;

    // ---------------- last-block finalize (256 threads), reusing LDS ----------------
    float* Gs = (float*)&S[0][0][0][0];       // [8][28][29]
    float* mx = Gs + NBATCH * 28 * 29;        // [8][50]
    float* my = mx + NBATCH * BINS;           // [8][50]  (total 29184 B < 38912 B)

    for (int idx = tid; idx < NBATCH * 784; idx += 256) {
        const int nn = idx / 784;
        const int rem = idx - nn * 784;
        const int r = rem / 28, c = rem - r * 28;
        // atomic RMW read: device-scope coherent view of all blocks' adds
        Gs[(nn * 28 + r) * 29 + c] = atomicAdd(&hg[nn * 1024 + r * 32 + c], 0.0f);
    }
    __syncthreads();

    // marginals: 800 tasks, 4-MAC band-dot (W row applied to G*(e1-e26))
    for (int t = tid; t < 2 * NBATCH * BINS; t += 256) {
        const int which = (t >= NBATCH * BINS) ? 1 : 0;
        const int t2 = which ? t - NBATCH * BINS : t;
        const int nn = t2 / BINS, b = t2 - nn * BINS;
        const int q = b >> 1;
        float w0, w1, w2, w3;
        if (b & 1) { w0 = -1.f; w1 = 9.f; w2 = -7.f; w3 = -1.f; }
        else       { w0 =  1.f; w1 = 7.f; w2 = -9.f; w3 =  1.f; }
        const float* G = &Gs[nn * 28 * 29];
        float m;
        if (which == 0) {
            m = w0 * (G[q * 29 + 1]       - G[q * 29 + 26])
              + w1 * (G[(q + 1) * 29 + 1] - G[(q + 1) * 29 + 26])
              + w2 * (G[(q + 2) * 29 + 1] - G[(q + 2) * 29 + 26])
              + w3 * (G[(q + 3) * 29 + 1] - G[(q + 3) * 29 + 26]);
            mx[nn * BINS + b] = m * 0.0625f;
        } else {
            m = w0 * (G[1 * 29 + q]       - G[26 * 29 + q])
              + w1 * (G[1 * 29 + q + 1]   - G[26 * 29 + q + 1])
              + w2 * (G[1 * 29 + q + 2]   - G[26 * 29 + q + 2])
              + w3 * (G[1 * 29 + q + 3]   - G[26 * 29 + q + 3]);
            my[nn * BINS + b] = m * 0.0625f;
        }
    }
    if (tid == 0) {
        float t = 0.f;
        for (int nn = 0; nn < NBATCH; ++nn) {
            const float* G = &Gs[nn * 28 * 29];
            t += G[1 * 29 + 1] - G[1 * 29 + 26] - G[26 * 29 + 1] + G[26 * 29 + 26];
        }
        sTv = t;
    }
    __syncthreads();

    // MI: 2x2 entry blocks share one 4x4 G block (8 n x 25 x 25 tasks)
    const float invT = 1.0f / sTv;
    const float invT2 = invT * invT;
    float mi = 0.f;
    for (int task = tid; task < NBATCH * 625; task += 256) {
        const int nn = task / 625;
        const int rem = task - nn * 625;
        const int bp = rem / 25, cp = rem - bp * 25;
        const float* G = &Gs[nn * 28 * 29];
        float g[4][4];
        #pragma unroll
        for (int r = 0; r < 4; ++r)
            #pragma unroll
            for (int s = 0; s < 4; ++s) g[r][s] = G[(bp + r) * 29 + (cp + s)];
        float rde[4], rdo[4];
        #pragma unroll
        for (int r = 0; r < 4; ++r) {
            rde[r] =  g[r][0] + 7.f * g[r][1] - 9.f * g[r][2] + g[r][3];
            rdo[r] = -g[r][0] + 9.f * g[r][1] - 7.f * g[r][2] - g[r][3];
        }
        const float hee = ( rde[0] + 7.f*rde[1] - 9.f*rde[2] + rde[3]) * (1.f/256.f);
        const float heo = ( rdo[0] + 7.f*rdo[1] - 9.f*rdo[2] + rdo[3]) * (1.f/256.f);
        const float hoe = (-rde[0] + 9.f*rde[1] - 7.f*rde[2] - rde[3]) * (1.f/256.f);
        const float hoo = (-rdo[0] + 9.f*rdo[1] - 7.f*rdo[2] - rdo[3]) * (1.f/256.f);
        const int b0 = 2 * bp, c0i = 2 * cp;
        {
            float p = hee * invT, jo = mx[nn * BINS + b0] * my[nn * BINS + c0i] * invT2;
            mi += p * (__logf(p + 1e-8f) - __logf(jo + 1e-8f));
        }
        {
            float p = heo * invT, jo = mx[nn * BINS + b0] * my[nn * BINS + c0i + 1] * invT2;
            mi += p * (__logf(p + 1e-8f) - __logf(jo + 1e-8f));
        }
        {
            float p = hoe * invT, jo = mx[nn * BINS + b0 + 1] * my[nn * BINS + c0i] * invT2;
            mi += p * (__logf(p + 1e-8f) - __logf(jo + 1e-8f));
        }
        {
            float p = hoo * invT, jo = mx[nn * BINS + b0 + 1] * my[nn * BINS + c0i + 1] * invT2;
            mi += p * (__logf(p + 1e-8f) - __logf(jo + 1e-8f));
        }
    }
    #pragma unroll
    for (int o = 32; o > 0; o >>= 1) mi += __shfl_down(mi, o, 64);
    if ((tid & 63) == 0) red[tid >> 6] = mi;
    __syncthreads();
    if (tid == 0) out[0] = red[0] + red[1] + red[2] + red[3];
}

extern "C" void kernel_launch(void* const* d_in, const int* in_sizes, int n_in,
                              void* d_out, int out_size, void* d_ws, size_t ws_size,
                              hipStream_t stream) {
    const float* im1 = (const float*)d_in[0];
    const float* im2 = (const float*)d_in[1];
    float* out = (float*)d_out;
    float* hg  = (float*)d_ws;                                  // [8][32][32] f32 = 32 KB
    unsigned* done = (unsigned*)((char*)d_ws + NBATCH * 1024 * sizeof(float));

    hipMemsetAsync(d_ws, 0, NBATCH * 1024 * sizeof(float) + sizeof(unsigned), stream);
    mi_kernel<<<dim3(KSLICES, NBATCH), dim3(256), 0, stream>>>(im1, im2, hg, done, out);
}

// Round 7
// 87.837 us; speedup vs baseline: 1.7662x; 1.7662x over previous
//
#include <hip/hip_runtime.h>

// Mutual information, N=8 images 384x384, 50 soft bins.
// K1 hgram: 28 even sigmoid edges per element (t_j = sigmoid(10v-0.2j), x256),
//   G = te_x . te_y^T via 16x16x32 MFMA (32x32-padded), atomic 28x28 epilogue.
// K2 finalize (1 block): hgram = W G W^T, W = D*M (cubic-interp odd edges,
//   4-banded {1,7,-9,1}/16 even rows, {-1,9,-7,-1}/16 odd rows); marginals
//   telescope (sum_b W[b] = e_1 - e_26); MI log-sum.
//
// R7: REVERT R6's fused single-kernel (fence + last-block finalize = 100us @
// 9% VALU — device-scope fence per block + forced vmcnt drains). Back to R5's
// proven 3-dispatch structure, plus: KC 128->256 (barriers/block 12->6),
// prefetch next (x,y) before the stage burst, 4-way split of the u*=e^0.4
// chain (dep chain 112->28 cyc). Harness ws-fill (~42us) is a fixed floor.

#define D_TOTAL   147456
#define NBATCH    8
#define BINS      50
#define NEDGE     28                       // even edges j=-2..52
#define KSLICES   192                      // slices per image
#define KC        256                      // d-columns per block iteration
#define SLICE_LEN (D_TOTAL / KSLICES)      // 768
#define ITERS     (SLICE_LEN / KC)         // 3
#define LDS_STR   280                      // 140 dwords = 12 mod 32: conflict-free b128 frags

typedef _Float16 half8 __attribute__((ext_vector_type(8)));
typedef float    f32x4 __attribute__((ext_vector_type(4)));

__global__ __launch_bounds__(256, 4) void hgram_kernel(const float* __restrict__ im1,
                                                       const float* __restrict__ im2,
                                                       float* __restrict__ hg) {
    __shared__ __align__(16) _Float16 Xs[32][LDS_STR];
    __shared__ __align__(16) _Float16 Ys[32][LDS_STR];

    const int tid   = threadIdx.x;
    const int slice = blockIdx.x;
    const int n     = blockIdx.y;
    const int base  = n * D_TOTAL + slice * SLICE_LEN;

    {   // zero pad rows 28..31 once (staging only rewrites rows 0..27)
        unsigned* px = (unsigned*)&Xs[28][0];
        unsigned* py = (unsigned*)&Ys[28][0];
        for (int i = tid; i < 4 * LDS_STR / 2; i += 256) { px[i] = 0u; py[i] = 0u; }
    }

    const int col  = tid;                     // 256 cols per iter, each thread does X and Y
    const int lane = tid & 63;
    const int w    = tid >> 6;
    const int r0   = (w & 1) << 4;            // G row strip (X edge)
    const int c0   = (w >> 1) << 4;           // G col strip (Y edge)
    const int frow = lane & 15;
    const int kg   = (lane >> 4) << 3;

    // stage one element -> 28 even-edge sigmoids (x256, f16), 4 independent u-chains
    auto stage1 = [&](float v, _Float16* dst) {
        const float E = __builtin_amdgcn_exp2f(v * -14.426950408889634f);  // e^{-10v}
        float u0 = E * 0.6703200460356393f;    // e^{-0.4}
        float u1 = E * 11.023176380641601f;    // e^{ 2.4}
        float u2 = E * 181.27224187515122f;    // e^{ 5.2}
        float u3 = E * 2980.9579870417283f;    // e^{ 8.0}
        #pragma unroll
        for (int k = 0; k < 7; ++k) {
            float t0 = __builtin_amdgcn_rcpf(__builtin_fmaf(u0, 0.00390625f, 0.00390625f));
            float t1 = __builtin_amdgcn_rcpf(__builtin_fmaf(u1, 0.00390625f, 0.00390625f));
            float t2 = __builtin_amdgcn_rcpf(__builtin_fmaf(u2, 0.00390625f, 0.00390625f));
            float t3 = __builtin_amdgcn_rcpf(__builtin_fmaf(u3, 0.00390625f, 0.00390625f));
            dst[(k)      * LDS_STR] = (_Float16)t0;   // 256/(1+u)
            dst[(7 + k)  * LDS_STR] = (_Float16)t1;
            dst[(14 + k) * LDS_STR] = (_Float16)t2;
            dst[(21 + k) * LDS_STR] = (_Float16)t3;
            u0 *= 1.4918246976412703f;   // e^{0.4}
            u1 *= 1.4918246976412703f;
            u2 *= 1.4918246976412703f;
            u3 *= 1.4918246976412703f;
        }
    };

    f32x4 acc = {0.f, 0.f, 0.f, 0.f};

    float vx = im1[base + col];
    float vy = im2[base + col];
    for (int it = 0; it < ITERS; ++it) {
        float nvx = 0.f, nvy = 0.f;
        if (it + 1 < ITERS) {                          // prefetch: in flight during stage
            nvx = im1[base + (it + 1) * KC + col];
            nvy = im2[base + (it + 1) * KC + col];
        }
        stage1(vx, &Xs[0][col]);
        stage1(vy, &Ys[0][col]);
        __syncthreads();
        #pragma unroll
        for (int ks = 0; ks < 8; ++ks) {
            const int k0 = ks * 32 + kg;
            half8 a = *(const half8*)&Xs[r0 + frow][k0];
            half8 b = *(const half8*)&Ys[c0 + frow][k0];
            acc = __builtin_amdgcn_mfma_f32_16x16x32_f16(a, b, acc, 0, 0, 0);
        }
        __syncthreads();
        vx = nvx; vy = nvy;
    }

    // epilogue: atomic-add the 28x28 region of G
    float* hgn = hg + n * 1024;
    const int gj = c0 + (lane & 15);
    const int ri = r0 + ((lane >> 4) << 2);
    if (gj < NEDGE) {
        #pragma unroll
        for (int r = 0; r < 4; ++r) {
            const int gi = ri + r;
            if (gi < NEDGE) atomicAdd(&hgn[gi * 32 + gj], acc[r]);
        }
    }
}

__global__ __launch_bounds__(1024) void finalize_kernel(const float* __restrict__ hg,
                                                        float* __restrict__ out) {
    __shared__ float Gs[NBATCH][NEDGE][29];   // stride 29 vs bank conflicts
    __shared__ float mx[NBATCH][BINS], my[NBATCH][BINS];
    __shared__ float red[16];
    __shared__ float sT;
    const int tid = threadIdx.x;

    for (int idx = tid; idx < NBATCH * NEDGE * NEDGE; idx += 1024) {
        int n = idx / (NEDGE * NEDGE);
        int rem = idx - n * (NEDGE * NEDGE);
        int r = rem / NEDGE, c = rem - r * NEDGE;
        Gs[n][r][c] = hg[n * 1024 + r * 32 + c];
    }
    __syncthreads();

    // marginals: 800 tasks, 4-MAC band-dot (W row applied to G*(e1-e26))
    if (tid < 2 * NBATCH * BINS) {
        const int which = (tid >= NBATCH * BINS) ? 1 : 0;
        const int t2 = which ? tid - NBATCH * BINS : tid;
        const int n = t2 / BINS, b = t2 - n * BINS;
        const int q = b >> 1;
        float w0, w1, w2, w3;
        if (b & 1) { w0 = -1.f; w1 = 9.f; w2 = -7.f; w3 = -1.f; }
        else       { w0 =  1.f; w1 = 7.f; w2 = -9.f; w3 =  1.f; }
        float m;
        if (which == 0) {
            m = w0 * (Gs[n][q][1]   - Gs[n][q][26])
              + w1 * (Gs[n][q+1][1] - Gs[n][q+1][26])
              + w2 * (Gs[n][q+2][1] - Gs[n][q+2][26])
              + w3 * (Gs[n][q+3][1] - Gs[n][q+3][26]);
            mx[n][b] = m * 0.0625f;
        } else {
            m = w0 * (Gs[n][1][q]   - Gs[n][26][q])
              + w1 * (Gs[n][1][q+1] - Gs[n][26][q+1])
              + w2 * (Gs[n][1][q+2] - Gs[n][26][q+2])
              + w3 * (Gs[n][1][q+3] - Gs[n][26][q+3]);
            my[n][b] = m * 0.0625f;
        }
    }
    if (tid == 0) {
        float t = 0.f;
        for (int n = 0; n < NBATCH; ++n)
            t += Gs[n][1][1] - Gs[n][1][26] - Gs[n][26][1] + Gs[n][26][26];
        sT = t;
    }
    __syncthreads();

    // MI pass: 2x2 entry blocks share one 4x4 G block (task = n, b-pair, c-pair)
    const float invT = 1.0f / sT;
    const float invT2 = invT * invT;
    float mi = 0.f;
    for (int task = tid; task < NBATCH * 25 * 25; task += 1024) {
        const int n = task / 625;
        const int rem = task - n * 625;
        const int bp = rem / 25, cp = rem - bp * 25;
        float g[4][4];
        #pragma unroll
        for (int r = 0; r < 4; ++r)
            #pragma unroll
            for (int s = 0; s < 4; ++s) g[r][s] = Gs[n][bp + r][cp + s];
        float rde[4], rdo[4];
        #pragma unroll
        for (int r = 0; r < 4; ++r) {
            rde[r] =  g[r][0] + 7.f * g[r][1] - 9.f * g[r][2] + g[r][3];
            rdo[r] = -g[r][0] + 9.f * g[r][1] - 7.f * g[r][2] - g[r][3];
        }
        const float hee = ( rde[0] + 7.f*rde[1] - 9.f*rde[2] + rde[3]) * (1.f/256.f);
        const float heo = ( rdo[0] + 7.f*rdo[1] - 9.f*rdo[2] + rdo[3]) * (1.f/256.f);
        const float hoe = (-rde[0] + 9.f*rde[1] - 7.f*rde[2] - rde[3]) * (1.f/256.f);
        const float hoo = (-rdo[0] + 9.f*rdo[1] - 7.f*rdo[2] - rdo[3]) * (1.f/256.f);
        const int b0 = 2 * bp, c0 = 2 * cp;
        {
            float p = hee * invT, jo = mx[n][b0] * my[n][c0] * invT2;
            mi += p * (__logf(p + 1e-8f) - __logf(jo + 1e-8f));
        }
        {
            float p = heo * invT, jo = mx[n][b0] * my[n][c0 + 1] * invT2;
            mi += p * (__logf(p + 1e-8f) - __logf(jo + 1e-8f));
        }
        {
            float p = hoe * invT, jo = mx[n][b0 + 1] * my[n][c0] * invT2;
            mi += p * (__logf(p + 1e-8f) - __logf(jo + 1e-8f));
        }
        {
            float p = hoo * invT, jo = mx[n][b0 + 1] * my[n][c0 + 1] * invT2;
            mi += p * (__logf(p + 1e-8f) - __logf(jo + 1e-8f));
        }
    }
    #pragma unroll
    for (int o = 32; o > 0; o >>= 1) mi += __shfl_down(mi, o, 64);
    if ((tid & 63) == 0) red[tid >> 6] = mi;
    __syncthreads();
    if (tid == 0) {
        float t = 0.f;
        for (int i = 0; i < 16; ++i) t += red[i];
        out[0] = t;
    }
}

extern "C" void kernel_launch(void* const* d_in, const int* in_sizes, int n_in,
                              void* d_out, int out_size, void* d_ws, size_t ws_size,
                              hipStream_t stream) {
    const float* im1 = (const float*)d_in[0];
    const float* im2 = (const float*)d_in[1];
    float* out = (float*)d_out;
    float* hg  = (float*)d_ws;   // [8][32][32] f32 = 32 KB

    hipMemsetAsync(d_ws, 0, NBATCH * 1024 * sizeof(float), stream);
    hgram_kernel<<<dim3(KSLICES, NBATCH), dim3(256), 0, stream>>>(im1, im2, hg);
    finalize_kernel<<<dim3(1), dim3(1024), 0, stream>>>(hg, out);
}

// Round 8
// 86.517 us; speedup vs baseline: 1.7931x; 1.0153x over previous
//
#include <hip/hip_runtime.h>

// Mutual information, N=8 images 384x384, 50 soft bins.
// K1 hgram: 28 even sigmoid edges per element (t_j = sigmoid(10v-0.2j), x256),
//   G = te_x . te_y^T via 16x16x32 MFMA (32x32-padded), atomic 28x28 epilogue.
// K2 finalize (1 block): hgram = W G W^T, W = D*M (cubic-interp odd edges,
//   4-banded {1,7,-9,1}/16 even rows, {-1,9,-7,-1}/16 odd rows); marginals
//   telescope (sum_b W[b] = e_1 - e_26); MI log-sum.
//
// R8 vs R7: KSLICES 192->96 (768 blocks = exactly 3/CU, single residency
// generation, no tail; epilogue atomics halved), seed table u_i = E*c_i
// (28 independent muls, no 7-deep dependent chains), X+Y staged in one fused
// loop (8 rcp streams in flight). Budget model: harness fill+overhead ~68us
// fixed; hgram ~15us is the remaining controllable piece.

#define D_TOTAL   147456
#define NBATCH    8
#define BINS      50
#define NEDGE     28                       // even edges j=-2..52
#define KSLICES   96                       // slices per image -> 768 blocks = 3/CU
#define KC        256                      // d-columns per block iteration
#define SLICE_LEN (D_TOTAL / KSLICES)      // 1536
#define ITERS     (SLICE_LEN / KC)         // 6
#define LDS_STR   280                      // 140 dwords = 12 mod 32: conflict-free b128 frags

typedef _Float16 half8 __attribute__((ext_vector_type(8)));
typedef float    f32x4 __attribute__((ext_vector_type(4)));

struct Tab { float c[NEDGE]; };
constexpr Tab make_tab() {
    Tab t{};
    double c = 0.6703200460356393;          // e^{-0.4} (edge j=-2)
    const double lam = 1.4918246976412703;  // e^{0.4} between even edges
    for (int i = 0; i < NEDGE; ++i) { t.c[i] = (float)c; c *= lam; }
    return t;
}
constexpr Tab TAB = make_tab();

__global__ __launch_bounds__(256, 3) void hgram_kernel(const float* __restrict__ im1,
                                                       const float* __restrict__ im2,
                                                       float* __restrict__ hg) {
    __shared__ __align__(16) _Float16 Xs[32][LDS_STR];
    __shared__ __align__(16) _Float16 Ys[32][LDS_STR];

    const int tid   = threadIdx.x;
    const int slice = blockIdx.x;
    const int n     = blockIdx.y;
    const int base  = n * D_TOTAL + slice * SLICE_LEN;

    {   // zero pad rows 28..31 once (staging only rewrites rows 0..27)
        unsigned* px = (unsigned*)&Xs[28][0];
        unsigned* py = (unsigned*)&Ys[28][0];
        for (int i = tid; i < 4 * LDS_STR / 2; i += 256) { px[i] = 0u; py[i] = 0u; }
    }

    const int col  = tid;                     // 256 cols/iter; each thread stages X and Y
    const int lane = tid & 63;
    const int w    = tid >> 6;
    const int r0   = (w & 1) << 4;            // G row strip (X edge)
    const int c0   = (w >> 1) << 4;           // G col strip (Y edge)
    const int frow = lane & 15;
    const int kg   = (lane >> 4) << 3;

    f32x4 acc = {0.f, 0.f, 0.f, 0.f};

    float vx = im1[base + col];
    float vy = im2[base + col];
    for (int it = 0; it < ITERS; ++it) {
        float nvx = 0.f, nvy = 0.f;
        if (it + 1 < ITERS) {                          // prefetch: in flight during stage
            nvx = im1[base + (it + 1) * KC + col];
            nvy = im2[base + (it + 1) * KC + col];
        }
        // ---- stage both elements: 28 even-edge sigmoids each (x256, f16) ----
        {
            const float Ex = __builtin_amdgcn_exp2f(vx * -14.426950408889634f); // e^{-10vx}
            const float Ey = __builtin_amdgcn_exp2f(vy * -14.426950408889634f); // e^{-10vy}
            _Float16* dx = &Xs[0][col];
            _Float16* dy = &Ys[0][col];
            #pragma unroll
            for (int i = 0; i < NEDGE; i += 4) {
                #pragma unroll
                for (int q = 0; q < 4; ++q) {
                    const float c = TAB.c[i + q];      // compile-time literal
                    float ux = c * Ex;                 // independent off Ex/Ey only
                    float uy = c * Ey;
                    float tx = __builtin_amdgcn_rcpf(__builtin_fmaf(ux, 0.00390625f, 0.00390625f));
                    float ty = __builtin_amdgcn_rcpf(__builtin_fmaf(uy, 0.00390625f, 0.00390625f));
                    dx[(i + q) * LDS_STR] = (_Float16)tx;   // 256/(1+u)
                    dy[(i + q) * LDS_STR] = (_Float16)ty;
                }
            }
        }
        __syncthreads();
        #pragma unroll
        for (int ks = 0; ks < 8; ++ks) {
            const int k0 = ks * 32 + kg;
            half8 a = *(const half8*)&Xs[r0 + frow][k0];
            half8 b = *(const half8*)&Ys[c0 + frow][k0];
            acc = __builtin_amdgcn_mfma_f32_16x16x32_f16(a, b, acc, 0, 0, 0);
        }
        __syncthreads();
        vx = nvx; vy = nvy;
    }

    // epilogue: atomic-add the 28x28 region of G
    float* hgn = hg + n * 1024;
    const int gj = c0 + (lane & 15);
    const int ri = r0 + ((lane >> 4) << 2);
    if (gj < NEDGE) {
        #pragma unroll
        for (int r = 0; r < 4; ++r) {
            const int gi = ri + r;
            if (gi < NEDGE) atomicAdd(&hgn[gi * 32 + gj], acc[r]);
        }
    }
}

__global__ __launch_bounds__(1024) void finalize_kernel(const float* __restrict__ hg,
                                                        float* __restrict__ out) {
    __shared__ float Gs[NBATCH][NEDGE][29];   // stride 29 vs bank conflicts
    __shared__ float mx[NBATCH][BINS], my[NBATCH][BINS];
    __shared__ float red[16];
    __shared__ float sT;
    const int tid = threadIdx.x;

    for (int idx = tid; idx < NBATCH * NEDGE * NEDGE; idx += 1024) {
        int n = idx / (NEDGE * NEDGE);
        int rem = idx - n * (NEDGE * NEDGE);
        int r = rem / NEDGE, c = rem - r * NEDGE;
        Gs[n][r][c] = hg[n * 1024 + r * 32 + c];
    }
    __syncthreads();

    // marginals: 800 tasks, 4-MAC band-dot (W row applied to G*(e1-e26))
    if (tid < 2 * NBATCH * BINS) {
        const int which = (tid >= NBATCH * BINS) ? 1 : 0;
        const int t2 = which ? tid - NBATCH * BINS : tid;
        const int n = t2 / BINS, b = t2 - n * BINS;
        const int q = b >> 1;
        float w0, w1, w2, w3;
        if (b & 1) { w0 = -1.f; w1 = 9.f; w2 = -7.f; w3 = -1.f; }
        else       { w0 =  1.f; w1 = 7.f; w2 = -9.f; w3 =  1.f; }
        float m;
        if (which == 0) {
            m = w0 * (Gs[n][q][1]   - Gs[n][q][26])
              + w1 * (Gs[n][q+1][1] - Gs[n][q+1][26])
              + w2 * (Gs[n][q+2][1] - Gs[n][q+2][26])
              + w3 * (Gs[n][q+3][1] - Gs[n][q+3][26]);
            mx[n][b] = m * 0.0625f;
        } else {
            m = w0 * (Gs[n][1][q]   - Gs[n][26][q])
              + w1 * (Gs[n][1][q+1] - Gs[n][26][q+1])
              + w2 * (Gs[n][1][q+2] - Gs[n][26][q+2])
              + w3 * (Gs[n][1][q+3] - Gs[n][26][q+3]);
            my[n][b] = m * 0.0625f;
        }
    }
    if (tid == 0) {
        float t = 0.f;
        for (int n = 0; n < NBATCH; ++n)
            t += Gs[n][1][1] - Gs[n][1][26] - Gs[n][26][1] + Gs[n][26][26];
        sT = t;
    }
    __syncthreads();

    // MI pass: 2x2 entry blocks share one 4x4 G block (task = n, b-pair, c-pair)
    const float invT = 1.0f / sT;
    const float invT2 = invT * invT;
    float mi = 0.f;
    for (int task = tid; task < NBATCH * 25 * 25; task += 1024) {
        const int n = task / 625;
        const int rem = task - n * 625;
        const int bp = rem / 25, cp = rem - bp * 25;
        float g[4][4];
        #pragma unroll
        for (int r = 0; r < 4; ++r)
            #pragma unroll
            for (int s = 0; s < 4; ++s) g[r][s] = Gs[n][bp + r][cp + s];
        float rde[4], rdo[4];
        #pragma unroll
        for (int r = 0; r < 4; ++r) {
            rde[r] =  g[r][0] + 7.f * g[r][1] - 9.f * g[r][2] + g[r][3];
            rdo[r] = -g[r][0] + 9.f * g[r][1] - 7.f * g[r][2] - g[r][3];
        }
        const float hee = ( rde[0] + 7.f*rde[1] - 9.f*rde[2] + rde[3]) * (1.f/256.f);
        const float heo = ( rdo[0] + 7.f*rdo[1] - 9.f*rdo[2] + rdo[3]) * (1.f/256.f);
        const float hoe = (-rde[0] + 9.f*rde[1] - 7.f*rde[2] - rde[3]) * (1.f/256.f);
        const float hoo = (-rdo[0] + 9.f*rdo[1] - 7.f*rdo[2] - rdo[3]) * (1.f/256.f);
        const int b0 = 2 * bp, c0 = 2 * cp;
        {
            float p = hee * invT, jo = mx[n][b0] * my[n][c0] * invT2;
            mi += p * (__logf(p + 1e-8f) - __logf(jo + 1e-8f));
        }
        {
            float p = heo * invT, jo = mx[n][b0] * my[n][c0 + 1] * invT2;
            mi += p * (__logf(p + 1e-8f) - __logf(jo + 1e-8f));
        }
        {
            float p = hoe * invT, jo = mx[n][b0 + 1] * my[n][c0] * invT2;
            mi += p * (__logf(p + 1e-8f) - __logf(jo + 1e-8f));
        }
        {
            float p = hoo * invT, jo = mx[n][b0 + 1] * my[n][c0 + 1] * invT2;
            mi += p * (__logf(p + 1e-8f) - __logf(jo + 1e-8f));
        }
    }
    #pragma unroll
    for (int o = 32; o > 0; o >>= 1) mi += __shfl_down(mi, o, 64);
    if ((tid & 63) == 0) red[tid >> 6] = mi;
    __syncthreads();
    if (tid == 0) {
        float t = 0.f;
        for (int i = 0; i < 16; ++i) t += red[i];
        out[0] = t;
    }
}

extern "C" void kernel_launch(void* const* d_in, const int* in_sizes, int n_in,
                              void* d_out, int out_size, void* d_ws, size_t ws_size,
                              hipStream_t stream) {
    const float* im1 = (const float*)d_in[0];
    const float* im2 = (const float*)d_in[1];
    float* out = (float*)d_out;
    float* hg  = (float*)d_ws;   // [8][32][32] f32 = 32 KB

    hipMemsetAsync(d_ws, 0, NBATCH * 1024 * sizeof(float), stream);
    hgram_kernel<<<dim3(KSLICES, NBATCH), dim3(256), 0, stream>>>(im1, im2, hg);
    finalize_kernel<<<dim3(1), dim3(1024), 0, stream>>>(hg, out);
}